// Round 1
// baseline (267.336 us; speedup 1.0000x reference)
//
#include <hip/hip_runtime.h>
#include <math.h>

// S4D scan, fp32 — round 7: even/odd time-phase split. One wave per (b,h)
// pair: lanes 0-31 run the even-output sub-chain, lanes 32-63 the odd one:
//   u_{t+2} = dA^2 u_t + dA dB x_{t+1-e} + dB x_{t+2-e}
// Exact linear-recurrence regrouping (no fix-up pass). 4096 waves -> 4
// waves/SIMD (2x occupancy), dependent chain halved per output, butterfly
// reduce halved per step (31 ops / 64 steps), TC=64 halves barrier rate.
// Block = 1024 thr = 16 pairs; grid 256 (1 block/CU, 16 waves/CU).

#define H_  512
#define L_  4096
#define B_  8
#define N2_ 32
#define TC  64           // timesteps per chunk
#define PPB 16           // pairs (waves) per block
#define THREADS 1024
#define NCHUNK (L_ / TC) // 64
#define XSTR 68          // x-tile row stride (floats): 64 + 4, 16B-aligned rows
#define YTSTR 67         // y-transpose row stride (67 mod 32 = 3: conflict-lite)

typedef float v2f __attribute__((ext_vector_type(2)));
typedef float v4f __attribute__((ext_vector_type(4)));

__device__ __forceinline__ float bfly1(float v) {   // xor 1: quad_perm [1,0,3,2]
    return __int_as_float(__builtin_amdgcn_update_dpp(
        0, __float_as_int(v), 0xB1, 0xf, 0xf, true));
}
__device__ __forceinline__ float bfly2(float v) {   // xor 2: quad_perm [2,3,0,1]
    return __int_as_float(__builtin_amdgcn_update_dpp(
        0, __float_as_int(v), 0x4E, 0xf, 0xf, true));
}
template <int M>
__device__ __forceinline__ float bflyswz(float v) { // xor M within 32-lane group
    return __int_as_float(__builtin_amdgcn_ds_swizzle(
        __float_as_int(v), (M << 10) | 0x1F));
}

// One double-step of both sub-chains (per-lane phase selects the x pair).
// u' = dAsq*u + (dAdB2*xa + dB2*xb), complex, all packed fp32 VOP3P.
#define SCAN_STEP(idx, XA, XM, XB) do {                                        \
      v2f xp;                                                                  \
      xp.x = phase ? (XM) : (XA);                                              \
      xp.y = phase ? (XB) : (XM);                                              \
      v2f m_, g_, t_, un_;                                                     \
      asm("v_pk_mul_f32 %0, %1, %2 op_sel:[0,1] op_sel_hi:[1,1]"               \
          : "=v"(m_) : "v"(dB2), "v"(xp));                                     \
      asm("v_pk_fma_f32 %0, %1, %2, %3 op_sel:[0,0,0] op_sel_hi:[1,0,1]"       \
          : "=v"(g_) : "v"(dAdB2), "v"(xp), "v"(m_));                          \
      asm("v_pk_fma_f32 %0, %1, %2, %3 op_sel:[1,1,0] op_sel_hi:[1,0,1] neg_lo:[1,0,0]" \
          : "=v"(t_) : "v"(dAsq), "v"(u), "v"(g_));                            \
      asm("v_pk_fma_f32 %0, %1, %2, %3 op_sel:[0,0,0] op_sel_hi:[0,1,1]"       \
          : "=v"(un_) : "v"(dAsq), "v"(u), "v"(t_));                           \
      u = un_;                                                                 \
      p[idx] = u.x;                                                            \
    } while (0)

__global__ __launch_bounds__(THREADS) void s4d_scan_kernel(
    const float* __restrict__ x,          // (B, L, H)
    const float* __restrict__ log_dt,     // (H,)
    const float* __restrict__ A_real_log, // (H, N2)
    const float* __restrict__ A_imag,     // (H, N2)
    const float* __restrict__ B_re,       // (H, N2)
    const float* __restrict__ B_im,       // (H, N2)
    const float* __restrict__ C_re,       // (H, N2)
    const float* __restrict__ C_im,       // (H, N2)
    const float* __restrict__ Dv,         // (H,)
    float* __restrict__ out_y,            // (B, L, H)
    float* __restrict__ st_re,            // (B, H, N2) real plane
    float* __restrict__ st_im)            // (B, H, N2) imag plane
{
    __shared__ __align__(16) float ldsX[2][PPB * XSTR];   // 2 x 4.25 KB
    __shared__ float ldsYT[2][PPB * YTSTR];               // 2 x 4.19 KB

    const int tid   = threadIdx.x;
    const int lane  = tid & 63;
    const int sub   = lane & 31;        // mode index
    const int phase = lane >> 5;        // 0 = even-time chain, 1 = odd-time
    const int q     = tid >> 6;         // pair (wave) within block, 0..15
    const int pair  = blockIdx.x * PPB + q;       // == b*H + h
    const int h     = pair & (H_ - 1);
    const int bblk  = blockIdx.x >> 5;            // 32 blocks per batch
    const int h0    = (blockIdx.x & 31) * PPB;    // block's h base

    // ---- per-lane constants (ZOH), mode n = sub; fold w = 2C into input ----
    const float dt = expf(log_dt[h]);
    const int hn = h * N2_ + sub;
    const float Ar = -expf(A_real_log[hn]);
    const float Ai = A_imag[hn];
    const float xr = dt * Ar;
    const float xi = dt * Ai;
    const float ex = expf(xr);
    const float cs = cosf(xi);
    const float sn = sinf(xi);
    const float dAr = ex * cs;
    const float dAi = ex * sn;
    // expm1(dtA)/A, cancellation-safe real part of expm1:
    const float sh  = sinf(0.5f * xi);
    const float emr = expm1f(xr) * cs - 2.0f * sh * sh;
    const float emi = ex * sn;
    const float ia  = 1.0f / (Ar * Ar + Ai * Ai);
    const float tr  = (emr * Ar + emi * Ai) * ia;
    const float ti  = (emi * Ar - emr * Ai) * ia;
    const float Brv = B_re[hn], Biv = B_im[hn];
    const float dBr = Brv * tr - Biv * ti;
    const float dBi = Brv * ti + Biv * tr;
    const float wr = 2.0f * C_re[hn];
    const float wi = 2.0f * C_im[hn];

    v2f dB2;                               // folded dB * w
    dB2.x = wr * dBr - wi * dBi;
    dB2.y = wr * dBi + wi * dBr;
    v2f dAdB2;                             // dA * (folded dB)
    dAdB2.x = dAr * dB2.x - dAi * dB2.y;
    dAdB2.y = dAr * dB2.y + dAi * dB2.x;
    v2f dAsq;                              // dA^2
    dAsq.x = dAr * dAr - dAi * dAi;
    dAsq.y = 2.0f * dAr * dAi;

    const float Dh = Dv[h];

    const float* __restrict__ xrow = x     + (size_t)bblk * L_ * H_ + h0;
    float*       __restrict__ yrow = out_y + (size_t)bblk * L_ * H_ + h0;

    const int j0 = tid >> 4;          // staging t-offset (0..63)
    const int p0 = tid & 15;          // staging h-offset

    // ---- prologue: stage chunk 0, prefetch chunk 1 ----
    float rx = xrow[(size_t)j0 * H_ + p0];
    ldsX[0][p0 * XSTR + j0] = rx;
    rx = xrow[(size_t)(TC + j0) * H_ + p0];
    __syncthreads();

    v2f u; u.x = 0.f; u.y = 0.f;      // folded state: 2C * state
    float xm1 = 0.f;                  // x_{-1} carry for the even chain

    const bool b1 = (sub & 1), b2 = (sub & 2), b4 = (sub & 4),
               b8 = (sub & 8), b16 = (sub & 16);

    for (int c = 0; c < NCHUNK; ++c) {
        const int cb = c & 1;

        // stage next chunk's x; issue global load for chunk c+2
        if (c + 1 < NCHUNK) ldsX[cb ^ 1][p0 * XSTR + j0] = rx;
        if (c + 2 < NCHUNK) rx = xrow[(size_t)((c + 2) * TC + j0) * H_ + p0];

        const v4f* xq = (const v4f*)&ldsX[cb][q * XSTR];   // wave-uniform base

        float p[32];

        // first half of the chunk's x (elements 0..31), broadcast b128 reads
        v4f a0[8];
#pragma unroll
        for (int i = 0; i < 8; ++i) a0[i] = xq[i];

#pragma unroll
        for (int t = 0; t < 16; ++t) {
            const float xaA = (t == 0) ? xm1
                              : a0[(2*t - 1) >> 2][(2*t - 1) & 3];
            const float xm  = a0[(2*t)     >> 2][(2*t)     & 3];
            const float xbB = a0[(2*t + 1) >> 2][(2*t + 1) & 3];
            SCAN_STEP(t, xaA, xm, xbB);
        }

        // second half (elements 32..63)
        v4f a1[8];
#pragma unroll
        for (int i = 0; i < 8; ++i) a1[i] = xq[8 + i];

#pragma unroll
        for (int t = 16; t < 32; ++t) {
            const float xaA = (t == 16) ? a0[7][3]
                              : a1[(2*t - 33) >> 2][(2*t - 33) & 3];
            const float xm  = a1[(2*t - 32) >> 2][(2*t - 32) & 3];
            const float xbB = a1[(2*t - 31) >> 2][(2*t - 31) & 3];
            SCAN_STEP(t, xaA, xm, xbB);
        }
        xm1 = a1[7][3];   // x_{c*64 + 63}, the next chunk's x_{-1}

        // ---- 5-stage distributed transpose-reduce over the 32 mode-lanes
        // (runs independently in each 32-lane half: A = even t, B = odd t) ----
#pragma unroll
        for (int j = 0; j < 32; j += 2) {
            const float keep = b1 ? p[j + 1] : p[j];
            const float send = b1 ? p[j] : p[j + 1];
            p[j] = keep + bfly1(send);
        }
#pragma unroll
        for (int j = 0; j < 32; j += 4) {
            const float keep = b2 ? p[j + 2] : p[j];
            const float send = b2 ? p[j] : p[j + 2];
            p[j] = keep + bfly2(send);
        }
#pragma unroll
        for (int j = 0; j < 32; j += 8) {
            const float keep = b4 ? p[j + 4] : p[j];
            const float send = b4 ? p[j] : p[j + 4];
            p[j] = keep + bflyswz<4>(send);
        }
#pragma unroll
        for (int j = 0; j < 32; j += 16) {
            const float keep = b8 ? p[j + 8] : p[j];
            const float send = b8 ? p[j] : p[j + 8];
            p[j] = keep + bflyswz<8>(send);
        }
        {
            const float keep = b16 ? p[16] : p[0];
            const float send = b16 ? p[0] : p[16];
            p[0] = keep + bflyswz<16>(send);
        }

        // ---- epilogue: lane holds y-sum for t = 2*sub + phase ----
        {
            const int myt  = (sub << 1) | phase;
            const float xv = ldsX[cb][q * XSTR + myt];
            const float y  = fmaf(Dh, xv, p[0]);
            // gelu(y) ~= y * sigmoid(2*sqrt(2/pi)*(y + 0.044715 y^3))
            // exp2-folded: g = y / (1 + exp2(y*(-cb*y^2 - ca)))
            const float y2  = y * y;
            const float arg = y * fmaf(-0.10294502f, y2, -2.30218425f);
            const float e   = __builtin_amdgcn_exp2f(arg);
            const float gy  = y * __builtin_amdgcn_rcpf(1.0f + e);
            ldsYT[cb][q * YTSTR + myt] = gy;
        }
        __syncthreads();   // YT visible; next x-tile staged; prev reads done

        // coalesced y store: thread e -> (t = e>>4, h = e&15), 64B rows
        yrow[(size_t)(c * TC + (tid >> 4)) * H_ + (tid & 15)] =
            ldsYT[cb][(tid & 15) * YTSTR + (tid >> 4)];
    }

    // ---- final state: odd chain's u == u_L (folded); unfold by conj(w)/|w|^2
    if (phase) {
        const float iw = 1.0f / (wr * wr + wi * wi);
        const float sr = (u.x * wr + u.y * wi) * iw;
        const float si = (u.y * wr - u.x * wi) * iw;
        st_re[(size_t)pair * N2_ + sub] = sr;
        st_im[(size_t)pair * N2_ + sub] = si;
    }
}

extern "C" void kernel_launch(void* const* d_in, const int* in_sizes, int n_in,
                              void* d_out, int out_size, void* d_ws, size_t ws_size,
                              hipStream_t stream) {
    (void)in_sizes; (void)n_in; (void)d_ws; (void)ws_size; (void)out_size;
    const float* x    = (const float*)d_in[0];
    const float* ldt  = (const float*)d_in[1];
    const float* Arl  = (const float*)d_in[2];
    const float* Aim  = (const float*)d_in[3];
    const float* Bre  = (const float*)d_in[4];
    const float* Bim  = (const float*)d_in[5];
    const float* Cre  = (const float*)d_in[6];
    const float* Cim  = (const float*)d_in[7];
    const float* Dv   = (const float*)d_in[8];
    float* out = (float*)d_out;
    float* st_re = out + (size_t)B_ * L_ * H_;       // ys first
    float* st_im = st_re + (size_t)B_ * H_ * N2_;    // then imag plane

    dim3 grid(B_ * H_ / PPB);   // 256 blocks (1 per CU), 16 waves each
    dim3 block(THREADS);        // 1024 threads = 16 pairs, 1 wave/pair
    hipLaunchKernelGGL(s4d_scan_kernel, grid, block, 0, stream,
                       x, ldt, Arl, Aim, Bre, Bim, Cre, Cim, Dv, out, st_re, st_im);
}